// Round 6
// baseline (109.975 us; speedup 1.0000x reference)
//
#include <hip/hip_runtime.h>
#include <hip/hip_bf16.h>
#include <math.h>

#define N_ 4096
#define B_ 4
#define C_ 64
#define MT 64                 // m-columns per attn block
#define NT 128                // n per step
#define STEPS (N_ / NT)       // 32
#define QSCALE 0.1803368801111137f   // 0.125 * log2(e), folded into Wq

typedef __attribute__((ext_vector_type(8))) short bf16x8;
typedef __attribute__((ext_vector_type(4))) float f32x4;
#define MFMA(a, b, c) __builtin_amdgcn_mfma_f32_16x16x32_bf16(a, b, c, 0, 0, 0)

#if __has_builtin(__builtin_amdgcn_exp2f)
#define EXP2(x) __builtin_amdgcn_exp2f(x)
#else
#define EXP2(x) __expf((x) * 0.6931471805599453f)
#endif

// bf16 round-half-up via bias+truncate (cheap; e never NaN/Inf)
static __device__ __forceinline__ uint hi_bits(float f) {
    return (__float_as_uint(f) + 0x8000u) >> 16;
}
static __device__ __forceinline__ float hi_val(float f) {
    return __uint_as_float((__float_as_uint(f) + 0x8000u) & 0xFFFF0000u);
}

// ---------------------------------------------------------------------------
// MFMA QKV projection (unchanged from R5). Block: one b, 32 n-cols; 4 waves x
// 3 row-tiles; x staged [c][n] in LDS; 3-pass hi/lo MFMA; Q/K/V hi-only bf16.
// ---------------------------------------------------------------------------
__global__ __launch_bounds__(256) void qkv_mfma(
    const float* __restrict__ x,  const float* __restrict__ Wq,
    const float* __restrict__ Wk, const float* __restrict__ Wv,
    ushort* __restrict__ Qh, ushort* __restrict__ Kh, ushort* __restrict__ Vh)
{
    __shared__ float xs[C_][33];

    const int b   = blockIdx.x / (N_ / 32);
    const int n0  = (blockIdx.x % (N_ / 32)) * 32;
    const int tid = threadIdx.x;
    const int w   = tid >> 6;
    const int l   = tid & 63;
    const int lr  = l & 15;
    const int lg  = l >> 4;

    #pragma unroll
    for (int it = 0; it < 2; ++it) {
        const int i = tid + it * 256;
        const int row = i >> 3, q = i & 7;
        const float4 a = *(const float4*)(x + ((size_t)b * C_ + row) * N_ + n0 + q * 4);
        xs[row][q * 4 + 0] = a.x; xs[row][q * 4 + 1] = a.y;
        xs[row][q * 4 + 2] = a.z; xs[row][q * 4 + 3] = a.w;
    }

    bf16x8 wh[3][2], wl[3][2];
    #pragma unroll
    for (int i = 0; i < 3; ++i) {
        const int rt  = w * 3 + i;
        const int mat = rt >> 2;          // 0=q 1=k 2=v
        const int dt  = rt & 3;
        const float* __restrict__ W = (mat == 0) ? Wq : ((mat == 1) ? Wk : Wv);
        const float scale = (mat == 0) ? QSCALE : 1.0f;
        #pragma unroll
        for (int ks = 0; ks < 2; ++ks) {
            const float4* p = (const float4*)(W + (dt * 16 + lr) * C_ + ks * 32 + lg * 8);
            float4 f0 = p[0], f1 = p[1];
            float v[8] = {f0.x, f0.y, f0.z, f0.w, f1.x, f1.y, f1.z, f1.w};
            bf16x8 ht, lt;
            #pragma unroll
            for (int j = 0; j < 8; ++j) {
                const float f = v[j] * scale;
                const float h = hi_val(f);
                ht[j] = (short)(__float_as_uint(h) >> 16);
                lt[j] = (short)hi_bits(f - h);
            }
            wh[i][ks] = ht; wl[i][ks] = lt;
        }
    }
    __syncthreads();

    #pragma unroll
    for (int nt = 0; nt < 2; ++nt) {
        bf16x8 xh[2], xl[2];
        #pragma unroll
        for (int ks = 0; ks < 2; ++ks) {
            bf16x8 ht, lt;
            #pragma unroll
            for (int j = 0; j < 8; ++j) {
                const float f = xs[ks * 32 + lg * 8 + j][nt * 16 + lr];
                const float h = hi_val(f);
                ht[j] = (short)(__float_as_uint(h) >> 16);
                lt[j] = (short)hi_bits(f - h);
            }
            xh[ks] = ht; xl[ks] = lt;
        }

        #pragma unroll
        for (int i = 0; i < 3; ++i) {
            const int rt  = w * 3 + i;
            const int mat = rt >> 2;
            const int dt  = rt & 3;
            f32x4 acc = (f32x4){0.f, 0.f, 0.f, 0.f};
            if (mat < 2) {
                #pragma unroll
                for (int ks = 0; ks < 2; ++ks) {
                    acc = MFMA(wh[i][ks], xh[ks], acc);
                    acc = MFMA(wh[i][ks], xl[ks], acc);
                    acc = MFMA(wl[i][ks], xh[ks], acc);
                }
                ushort* __restrict__ H = mat ? Kh : Qh;
                const size_t base = ((size_t)b * N_ + n0 + nt * 16 + lr) * C_ + dt * 16 + lg * 4;
                *(uint2*)(H + base) = make_uint2((hi_bits(acc[1]) << 16) | hi_bits(acc[0]),
                                                 (hi_bits(acc[3]) << 16) | hi_bits(acc[2]));
            } else {
                #pragma unroll
                for (int ks = 0; ks < 2; ++ks) {
                    acc = MFMA(xh[ks], wh[i][ks], acc);
                    acc = MFMA(xl[ks], wh[i][ks], acc);
                    acc = MFMA(xh[ks], wl[i][ks], acc);
                }
                const size_t base = ((size_t)b * C_ + dt * 16 + lr) * N_ + n0 + nt * 16 + lg * 4;
                *(uint2*)(Vh + base) = make_uint2((hi_bits(acc[1]) << 16) | hi_bits(acc[0]),
                                                  (hi_bits(acc[3]) << 16) | hi_bits(acc[2]));
            }
        }
    }
}

// ---------------------------------------------------------------------------
// Producer/consumer attention: 16 waves (1024 thr), 4 waves/SIMD.
// Waves 0-7: S = Q·K (16 n-rows each of the 128-step), exp2 -> bf16 E into
// rotation-swizzled double-buffered LDS. Waves 8-15: PV from Em (o-tile =
// pw&3, n-half = pw>>2). One barrier per step. Epilogue: den via LDS from
// S-waves; oacc pair-reduction (nh=1 -> LDS scratch reusing Em; nh=0 writes).
// ---------------------------------------------------------------------------
__global__ __launch_bounds__(1024) void attn_mfma(
    const ushort* __restrict__ Qh, const ushort* __restrict__ Kh,
    const ushort* __restrict__ Vh, float* __restrict__ out)
{
    __shared__ ushort Em[2][MT * NT];     // 32 KB; reused as f32 scratch at end
    __shared__ float red[8][MT];

    // XCD swizzle: blocks of batch b land on XCDs {2b,2b+1}
    const int bid = blockIdx.x;
    const int b   = (bid & 7) >> 1;
    const int mt  = (bid & 1) + ((bid >> 3) << 1);
    const int tid = threadIdx.x;
    const int w   = tid >> 6;             // 0..15
    const int l   = tid & 63;
    const int lr  = l & 15;
    const int lg  = l >> 4;
    const int m0  = mt * MT;

    const bool sW = (w < 8);
    const int pw  = w & 7;                // PV waves: pw = w-8
    const int ot  = pw & 3;               // o-tile
    const int nh  = pw >> 2;              // n-half (ks base = nh*2)

    bf16x8 khf[4][2];                     // S-waves
    float  den[4] = {0.f, 0.f, 0.f, 0.f};
    f32x4  oacc[4];                       // PV-waves
    #pragma unroll
    for (int f = 0; f < 4; ++f) oacc[f] = (f32x4){0.f, 0.f, 0.f, 0.f};
    bf16x8 vcur[2];

    if (sW) {
        // resident K B-frags
        #pragma unroll
        for (int f = 0; f < 4; ++f)
            #pragma unroll
            for (int ks = 0; ks < 2; ++ks)
                khf[f][ks] = *(const bf16x8*)(Kh + ((size_t)b * N_ + m0 + f * 16 + lr) * C_ + ks * 32 + lg * 8);

        // S(0) -> Em[0]
        bf16x8 q[2];
        #pragma unroll
        for (int ks = 0; ks < 2; ++ks)
            q[ks] = *(const bf16x8*)(Qh + ((size_t)b * N_ + w * 16 + lr) * C_ + ks * 32 + lg * 8);
        f32x4 s[4];
        #pragma unroll
        for (int f = 0; f < 4; ++f) s[f] = (f32x4){0.f, 0.f, 0.f, 0.f};
        __builtin_amdgcn_s_setprio(1);
        #pragma unroll
        for (int ks = 0; ks < 2; ++ks)
            #pragma unroll
            for (int f = 0; f < 4; ++f) s[f] = MFMA(q[ks], khf[f][ks], s[f]);
        __builtin_amdgcn_s_setprio(0);
        #pragma unroll
        for (int f = 0; f < 4; ++f) {
            const float e0 = EXP2(s[f][0]), e1 = EXP2(s[f][1]);
            const float e2 = EXP2(s[f][2]), e3 = EXP2(s[f][3]);
            den[f] += (e0 + e1) + (e2 + e3);
            const uint u0 = __float_as_uint(e0) + 0x8000u;
            const uint u1 = __float_as_uint(e1) + 0x8000u;
            const uint u2 = __float_as_uint(e2) + 0x8000u;
            const uint u3 = __float_as_uint(e3) + 0x8000u;
            const int row = f * 16 + lr;
            const int g   = w * 2 + (lg >> 1);
            *(uint2*)&Em[0][row * NT + (((g + row) & 15) << 3) + ((lg & 1) << 2)] =
                make_uint2((u1 & 0xFFFF0000u) | (u0 >> 16), (u3 & 0xFFFF0000u) | (u2 >> 16));
        }
    } else {
        #pragma unroll
        for (int k2 = 0; k2 < 2; ++k2)
            vcur[k2] = *(const bf16x8*)(Vh + ((size_t)b * C_ + ot * 16 + lr) * N_ + nh * 64 + k2 * 32 + lg * 8);
    }
    __syncthreads();

    for (int t = 0; t < STEPS; ++t) {
        if (sW) {
            if (t + 1 < STEPS) {
                bf16x8 q[2];
                #pragma unroll
                for (int ks = 0; ks < 2; ++ks)
                    q[ks] = *(const bf16x8*)(Qh + ((size_t)b * N_ + (t + 1) * NT + w * 16 + lr) * C_ + ks * 32 + lg * 8);
                f32x4 s[4];
                #pragma unroll
                for (int f = 0; f < 4; ++f) s[f] = (f32x4){0.f, 0.f, 0.f, 0.f};
                __builtin_amdgcn_s_setprio(1);
                #pragma unroll
                for (int ks = 0; ks < 2; ++ks)
                    #pragma unroll
                    for (int f = 0; f < 4; ++f) s[f] = MFMA(q[ks], khf[f][ks], s[f]);
                __builtin_amdgcn_s_setprio(0);
                const int buf = (t + 1) & 1;
                #pragma unroll
                for (int f = 0; f < 4; ++f) {
                    const float e0 = EXP2(s[f][0]), e1 = EXP2(s[f][1]);
                    const float e2 = EXP2(s[f][2]), e3 = EXP2(s[f][3]);
                    den[f] += (e0 + e1) + (e2 + e3);
                    const uint u0 = __float_as_uint(e0) + 0x8000u;
                    const uint u1 = __float_as_uint(e1) + 0x8000u;
                    const uint u2 = __float_as_uint(e2) + 0x8000u;
                    const uint u3 = __float_as_uint(e3) + 0x8000u;
                    const int row = f * 16 + lr;
                    const int g   = w * 2 + (lg >> 1);
                    *(uint2*)&Em[buf][row * NT + (((g + row) & 15) << 3) + ((lg & 1) << 2)] =
                        make_uint2((u1 & 0xFFFF0000u) | (u0 >> 16), (u3 & 0xFFFF0000u) | (u2 >> 16));
                }
            }
        } else {
            // prefetch next V while PV(t) runs
            const int tv = (t + 1 < STEPS) ? t + 1 : t;
            bf16x8 vnext[2];
            #pragma unroll
            for (int k2 = 0; k2 < 2; ++k2)
                vnext[k2] = *(const bf16x8*)(Vh + ((size_t)b * C_ + ot * 16 + lr) * N_ + (size_t)tv * NT + nh * 64 + k2 * 32 + lg * 8);
            __builtin_amdgcn_s_setprio(1);
            #pragma unroll
            for (int k2 = 0; k2 < 2; ++k2)
                #pragma unroll
                for (int f = 0; f < 4; ++f) {
                    const int row = f * 16 + lr;
                    const int lgc = (nh * 2 + k2) * 4 + lg;
                    const bf16x8 eb = *(const bf16x8*)&Em[t & 1][row * NT + (((lgc + row) & 15) << 3)];
                    oacc[f] = MFMA(vcur[k2], eb, oacc[f]);
                }
            __builtin_amdgcn_s_setprio(0);
            vcur[0] = vnext[0]; vcur[1] = vnext[1];
        }
        __syncthreads();
    }

    // ---- epilogue ----
    if (sW) {
        #pragma unroll
        for (int f = 0; f < 4; ++f) {
            den[f] += __shfl_xor(den[f], 16);
            den[f] += __shfl_xor(den[f], 32);
        }
        if (lg == 0)
            #pragma unroll
            for (int f = 0; f < 4; ++f) red[w][f * 16 + lr] = den[f];
    } else if (nh == 1) {
        float* scr = (float*)&Em[0][0];           // Em no longer needed
        #pragma unroll
        for (int f = 0; f < 4; ++f)
            #pragma unroll
            for (int r = 0; r < 4; ++r)
                scr[(ot * 16 + lg * 4 + r) * 65 + f * 16 + lr] = oacc[f][r];
    }
    __syncthreads();

    if (!sW && nh == 0) {
        const float* scr = (const float*)&Em[0][0];
        float inv[4];
        #pragma unroll
        for (int f = 0; f < 4; ++f) {
            const int m = f * 16 + lr;
            inv[f] = __builtin_amdgcn_rcpf(red[0][m] + red[1][m] + red[2][m] + red[3][m] +
                                           red[4][m] + red[5][m] + red[6][m] + red[7][m]);
        }
        #pragma unroll
        for (int f = 0; f < 4; ++f)
            #pragma unroll
            for (int r = 0; r < 4; ++r) {
                const int o = ot * 16 + lg * 4 + r;
                out[((size_t)b * C_ + o) * N_ + m0 + f * 16 + lr] =
                    (oacc[f][r] + scr[o * 65 + f * 16 + lr]) * inv[f];
            }
    }
}

// ---------------------------------------------------------------------------
extern "C" void kernel_launch(void* const* d_in, const int* in_sizes, int n_in,
                              void* d_out, int out_size, void* d_ws, size_t ws_size,
                              hipStream_t stream)
{
    const float* x  = (const float*)d_in[0];
    const float* Wq = (const float*)d_in[1];
    const float* Wk = (const float*)d_in[2];
    const float* Wv = (const float*)d_in[3];
    float* out = (float*)d_out;

    const size_t NE = (size_t)B_ * N_ * C_;
    ushort* Qh = (ushort*)d_ws;
    ushort* Kh = Qh + NE;
    ushort* Vh = Kh + NE;

    qkv_mfma<<<B_ * (N_ / 32), 256, 0, stream>>>(x, Wq, Wk, Wv, Qh, Kh, Vh);
    attn_mfma<<<B_ * (N_ / MT), 1024, 0, stream>>>(Qh, Kh, Vh, out);
}